// Round 2
// baseline (200.823 us; speedup 1.0000x reference)
//
#include <hip/hip_runtime.h>
#include <hip/hip_bf16.h>
#include <math.h>

// FreqActivation — harness compares only the REAL part of the complex64 ref
// (complex -> float32 cast drops imag; out_size = B*H*W*C = 16,777,216).
// real(out[b,h,w,c]) = relu(amp_raw)*cos(pi*tanh(ph_raw)) at source
//   (h,w)            if h+w <= 256   [top region + borders]
//   (256-h, 256-w)   if h+w >= 257   [mirrored bottom; conj doesn't affect real]
// Input [8,256,256,32,2] float32: 64 floats per (b,h,w), interleaved (amp,ph).
// Output [8,256,256,32] float32: 32 floats per (b,h,w).
//
// Round-1 lesson: mirror re-reads are L3-absorbed (input 128 MiB < 256 MiB L3);
// dedup-by-double-store REGRESSED (half-empty waves + second write stream).
// Keep the one-thread-one-output mapping; attack LATENCY instead:
//   - 4 outputs per thread at wave-stride (8 independent 16B loads in flight,
//     every instruction still fully coalesced: contiguous 1 KiB per wave)
//   - non-temporal stores (output never re-read; don't evict the input
//     triangle from L2/L3 — the mirror re-read hits are the win)

#define PI_F 3.14159265358979323846f

typedef float f32x4 __attribute__((ext_vector_type(4)));

__global__ __launch_bounds__(256) void freq_act_kernel(
    const float* __restrict__ in, float* __restrict__ out, int n_vec4)
{
    // block covers 1024 consecutive output float4s; thread t owns
    // {base+t, base+t+256, base+t+512, base+t+768}
    const int base = blockIdx.x * 1024 + threadIdx.x;

    const float* src[4];
    float4 v0[4], v1[4];
    bool live[4];

#pragma unroll
    for (int k = 0; k < 4; ++k) {
        const int j = base + (k << 8);
        live[k] = (j < n_vec4) && ((j >> 19) < 8);
        if (live[k]) {
            const int c4 = j & 7;
            const int w  = (j >> 3)  & 255;
            const int h  = (j >> 11) & 255;
            const int b  = j >> 19;
            const bool top = (h + w) <= 256;
            const int  sh  = top ? h : 256 - h;
            const int  sw  = top ? w : 256 - w;
            src[k] = in + (((size_t)((b * 256 + sh) * 256 + sw)) << 6) + (c4 << 3);
        }
    }

    // issue all 8 loads back-to-back for maximum memory-level parallelism
#pragma unroll
    for (int k = 0; k < 4; ++k) {
        if (live[k]) {
            v0[k] = *reinterpret_cast<const float4*>(src[k]);
            v1[k] = *reinterpret_cast<const float4*>(src[k] + 4);
        }
    }

#pragma unroll
    for (int k = 0; k < 4; ++k) {
        if (live[k]) {
            const int j = base + (k << 8);
            f32x4 o;
            o.x = fmaxf(v0[k].x, 0.0f) * __cosf(PI_F * tanhf(v0[k].y));
            o.y = fmaxf(v0[k].z, 0.0f) * __cosf(PI_F * tanhf(v0[k].w));
            o.z = fmaxf(v1[k].x, 0.0f) * __cosf(PI_F * tanhf(v1[k].y));
            o.w = fmaxf(v1[k].z, 0.0f) * __cosf(PI_F * tanhf(v1[k].w));
            __builtin_nontemporal_store(
                o, reinterpret_cast<f32x4*>(out + ((size_t)j << 2)));
        }
    }
}

extern "C" void kernel_launch(void* const* d_in, const int* in_sizes, int n_in,
                              void* d_out, int out_size, void* d_ws, size_t ws_size,
                              hipStream_t stream)
{
    const float* in = (const float*)d_in[0];
    float* out = (float*)d_out;

    const int n_vec4 = out_size / 4;          // expected 4,194,304
    const int block = 256;
    const int per_block = 1024;               // 4 float4 outputs per thread
    const int grid = (n_vec4 + per_block - 1) / per_block;

    freq_act_kernel<<<grid, block, 0, stream>>>(in, out, n_vec4);
}

// Round 3
// 197.567 us; speedup vs baseline: 1.0165x; 1.0165x over previous
//
#include <hip/hip_runtime.h>
#include <hip/hip_bf16.h>
#include <math.h>

// FreqActivation — harness compares only the REAL part of the complex64 ref
// (complex -> float32 cast drops imag; out_size = B*H*W*C = 16,777,216).
// real(out[b,h,w,c]) = relu(amp_raw)*cos(pi*tanh(ph_raw)) at source
//   (h,w)            if h+w <= 256   [top region + borders]
//   (256-h, 256-w)   if h+w >= 257   [mirrored bottom; conj doesn't affect real]
// Input [8,256,256,32,2] float32: 64 floats per (b,h,w), interleaved (amp,ph).
// Output [8,256,256,32] float32: 32 floats per (b,h,w).
//
// Session ledger:
//  R0 (1 float4/thread, plain stores)             : 194.8 us  <- best so far
//  R1 (dedup + mirror double-store)               : 199.4 us  (mirror reads were
//      already L3-absorbed; paid for half-empty waves + 2nd write stream)
//  R2 (4x strided ILP + live[] masks + NT stores) : 200.8 us  (NT stores bypass
//      L2 write-coalescing; predication overhead)
//  R3 (this): single-variable change vs R0 — coarsen 2x with CONSECUTIVE
//      addressing, plain stores. 4 independent loads/thread (2x MLP), half the
//      address math and wave count, identical byte-level access pattern.

#define PI_F 3.14159265358979323846f

__global__ __launch_bounds__(256) void freq_act_kernel(
    const float* __restrict__ in, float* __restrict__ out, int n_pair)
{
    const int tid = blockIdx.x * 256 + threadIdx.x;  // one thread = 2 output float4s
    if (tid >= n_pair) return;

    const int c2 = tid & 3;           // which 16-float chunk of the 32-float row
    const int w  = (tid >> 2)  & 255;
    const int h  = (tid >> 10) & 255;
    const int b  = tid >> 18;
    if (b >= 8) return;               // crash-proof if out_size semantics differ

    const bool top = (h + w) <= 256;
    const int  sh  = top ? h : 256 - h;
    const int  sw  = top ? w : 256 - w;

    // input row: 64 floats; this thread needs floats [c2*16, c2*16+16)
    const float* src = in + (((size_t)((b * 256 + sh) * 256 + sw)) << 6) + (c2 << 4);
    const float4 v0 = *reinterpret_cast<const float4*>(src);
    const float4 v1 = *reinterpret_cast<const float4*>(src + 4);
    const float4 v2 = *reinterpret_cast<const float4*>(src + 8);
    const float4 v3 = *reinterpret_cast<const float4*>(src + 12);

    float4 o0, o1;
    o0.x = fmaxf(v0.x, 0.0f) * __cosf(PI_F * tanhf(v0.y));
    o0.y = fmaxf(v0.z, 0.0f) * __cosf(PI_F * tanhf(v0.w));
    o0.z = fmaxf(v1.x, 0.0f) * __cosf(PI_F * tanhf(v1.y));
    o0.w = fmaxf(v1.z, 0.0f) * __cosf(PI_F * tanhf(v1.w));
    o1.x = fmaxf(v2.x, 0.0f) * __cosf(PI_F * tanhf(v2.y));
    o1.y = fmaxf(v2.z, 0.0f) * __cosf(PI_F * tanhf(v2.w));
    o1.z = fmaxf(v3.x, 0.0f) * __cosf(PI_F * tanhf(v3.y));
    o1.w = fmaxf(v3.z, 0.0f) * __cosf(PI_F * tanhf(v3.w));

    float* dst = out + ((size_t)tid << 3);
    *reinterpret_cast<float4*>(dst)     = o0;
    *reinterpret_cast<float4*>(dst + 4) = o1;
}

extern "C" void kernel_launch(void* const* d_in, const int* in_sizes, int n_in,
                              void* d_out, int out_size, void* d_ws, size_t ws_size,
                              hipStream_t stream)
{
    const float* in = (const float*)d_in[0];
    float* out = (float*)d_out;

    const int n_pair = out_size / 8;          // expected 2,097,152
    const int block = 256;
    const int grid = (n_pair + block - 1) / block;

    freq_act_kernel<<<grid, block, 0, stream>>>(in, out, n_pair);
}

// Round 4
// 195.234 us; speedup vs baseline: 1.0286x; 1.0120x over previous
//
#include <hip/hip_runtime.h>
#include <hip/hip_bf16.h>
#include <math.h>

// FreqActivation — harness compares only the REAL part of the complex64 ref
// (complex -> float32 cast drops imag; out_size = B*H*W*C = 16,777,216).
// real(out[b,h,w,c]) = relu(amp_raw)*cos(pi*tanh(ph_raw)) at source
//   (h,w)            if h+w <= 256   [top region + borders]
//   (256-h, 256-w)   if h+w >= 257   [mirrored bottom; conj doesn't affect real]
// Input [8,256,256,32,2] float32: 64 floats per (b,h,w), interleaved (amp,ph).
// Output [8,256,256,32] float32: 32 floats per (b,h,w).
// One thread = one output float4 (4 channels) = two input float4 loads.
//
// Session ledger (kernel portion = dur_us minus ~160 us harness fills):
//  R0 (this structure)                            : 194.8 us (~34 us kernel) BEST
//  R1 (dedup + mirror double-store)               : 199.4 us — mirror reads were
//      already L3-absorbed; paid half-empty waves + 2nd write stream
//  R2 (4x strided ILP + live[] masks + NT stores) : 200.8 us — NT stores bypass
//      L2 write-coalescing; predication overhead
//  R3 (2x consecutive coarsening)                 : 197.6 us — neutral; MLP is
//      not the limiter
// Conclusion: ~129 MiB unique HBM traffic + ~64 MiB L3-served mirror re-reads
// puts the floor at ~25-30 us; measured ~34 us incl. launch/tail. Remaining gap
// (<5 us of 195 total) is inside observed run noise. STRUCTURAL FLOOR.

#define PI_F 3.14159265358979323846f

__global__ __launch_bounds__(256) void freq_act_kernel(
    const float* __restrict__ in, float* __restrict__ out, int n_vec4)
{
    const int tid = blockIdx.x * 256 + threadIdx.x;
    if (tid >= n_vec4) return;

    const int c4 = tid & 7;           // which output float4 within the 32-float row
    const int w  = (tid >> 3)  & 255;
    const int h  = (tid >> 11) & 255;
    const int b  = tid >> 19;
    if (b >= 8) return;               // crash-proof if out_size semantics differ

    const bool top = (h + w) <= 256;
    const int  sh  = top ? h : 256 - h;
    const int  sw  = top ? w : 256 - w;

    // input row: 64 floats; this thread needs floats [c4*8, c4*8+8)
    const float* src = in + (((size_t)((b * 256 + sh) * 256 + sw)) << 6) + (c4 << 3);
    const float4 v0 = *reinterpret_cast<const float4*>(src);
    const float4 v1 = *reinterpret_cast<const float4*>(src + 4);

    float4 o;
    o.x = fmaxf(v0.x, 0.0f) * __cosf(PI_F * tanhf(v0.y));
    o.y = fmaxf(v0.z, 0.0f) * __cosf(PI_F * tanhf(v0.w));
    o.z = fmaxf(v1.x, 0.0f) * __cosf(PI_F * tanhf(v1.y));
    o.w = fmaxf(v1.z, 0.0f) * __cosf(PI_F * tanhf(v1.w));
    *reinterpret_cast<float4*>(out + ((size_t)tid << 2)) = o;
}

extern "C" void kernel_launch(void* const* d_in, const int* in_sizes, int n_in,
                              void* d_out, int out_size, void* d_ws, size_t ws_size,
                              hipStream_t stream)
{
    const float* in = (const float*)d_in[0];
    float* out = (float*)d_out;

    const int n_vec4 = out_size / 4;          // expected 4,194,304
    const int block = 256;
    const int grid = (n_vec4 + block - 1) / block;

    freq_act_kernel<<<grid, block, 0, stream>>>(in, out, n_vec4);
}